// Round 6
// baseline (353.264 us; speedup 1.0000x reference)
//
#include <hip/hip_runtime.h>
#include <hip/hip_bf16.h>
#include <math.h>

#define B_    2
#define S_    2048
#define HID_  2048
#define H_    16
#define HKV_  4
#define HD_   128
#define BS_   (B_*S_)
#define QSTRIDE 3072          // fused qkv row: [q 2048 | k 512 | v 512]
#define L2E 1.4426950408889634f

typedef __attribute__((ext_vector_type(8))) short bf16x8;
typedef __attribute__((ext_vector_type(4))) float f32x4;
typedef __attribute__((ext_vector_type(16))) float f32x16;
typedef unsigned int uint;

typedef __attribute__((address_space(3))) void lds_void;
typedef __attribute__((address_space(1))) const void gbl_cvoid;

__device__ __forceinline__ void load_lds16(const void* g, void* l) {
  __builtin_amdgcn_global_load_lds((gbl_cvoid*)g, (lds_void*)l, 16, 0, 0);
}

__device__ __forceinline__ unsigned short f2bf(float f) {
  uint u = __float_as_uint(f);
  u = (u + 0x7fff + ((u >> 16) & 1)) >> 16;   // RNE
  return (unsigned short)u;
}
__device__ __forceinline__ float bf2f(unsigned short u) {
  return __uint_as_float(((uint)u) << 16);
}
__device__ __forceinline__ uint cvtpk_bf16(float lo, float hi) {
  uint r;
  asm("v_cvt_pk_bf16_f32 %0, %1, %2" : "=v"(r) : "v"(lo), "v"(hi));
  return r;
}
__device__ __forceinline__ void swap32(uint& a, uint& b) {
  asm("v_permlane32_swap_b32 %0, %1" : "+v"(a), "+v"(b));
}

// ---------------------------------------------------------------------------
// fp32 -> bf16 cast
// ---------------------------------------------------------------------------
__global__ __launch_bounds__(256) void cast_f32_bf16(
    const float* __restrict__ src, unsigned short* __restrict__ dst, int n)
{
  int i = (blockIdx.x * 256 + threadIdx.x) * 4;
  if (i < n) {
    float4 v = *(const float4*)(src + i);
    ushort4 o;
    o.x = f2bf(v.x); o.y = f2bf(v.y); o.z = f2bf(v.z); o.w = f2bf(v.w);
    *(ushort4*)(dst + i) = o;
  }
}

// ---------------------------------------------------------------------------
// bf16 NT-GEMM, 256-row tile, BK=64, 512 threads (8 waves, 2M x 4N),
// DEEP-PREFETCH counted-vmcnt schedule (T3+T4) + setprio (T5) + XCD swizzle
// (T1). C[M][N] = A[M][K] @ W[N][K]^T, fp32 accum, MFMA 16x16x32.
//
// Schedule per tile t (all of tile t+1's staging issued DURING tile t):
//   top:  vmcnt(KLO_OUT) + barrier   -> t's klo slab landed
//         issue klo(t+1) glds        -> awaited at top of t+1 (4 phases away)
//   ph1 (slab0, mh0 MFMA)
//         issue khi(t+1) glds        -> awaited at mid of t+1 (5 phases away)
//   ph2 (slab0, mh1 MFMA)
//   mid:  vmcnt(KHI_OUT) + barrier   -> t's khi slab landed
//   ph3/ph4 (slab1)
// Issue->wait distance 4-6 phases (~620-930 SIMD-cyc) covers L2/HBM latency.
// BN=256: top vmcnt(4), mid vmcnt(8).  BN=128: top vmcnt(3), mid vmcnt(6).
// ---------------------------------------------------------------------------
template <int BN, int WRITE_BF16>
__global__ __launch_bounds__(512, 2) void gemm_nt_dp(
    const unsigned short* __restrict__ A, const unsigned short* __restrict__ W,
    void* __restrict__ Cv, int M, int N, int K)
{
  constexpr int ASLAB = 16384;            // 256 rows x 64 B
  constexpr int BSLAB = BN * 64;
  constexpr int ABUF  = 2 * ASLAB;
  constexpr int BBUF  = 2 * BSLAB;
  constexpr int RN    = BN / 4;           // per-wave N
  constexpr int NTN   = RN / 16;          // n-tiles per wave (4 or 2)

  __shared__ __align__(16) char lds_[2 * ABUF + 2 * BBUF];
  char* const AL = lds_;
  char* const BL = lds_ + 2 * ABUF;

  const int tid = threadIdx.x;
  const int lane = tid & 63;
  const int wid = tid >> 6;
  const int wm = wid >> 2, wn = wid & 3;
  const int c_ = lane & 15, g4 = lane >> 4;

  // XCD-aware swizzle: blocks with flat%8==r form one contiguous tile chunk
  const int gx = gridDim.x;
  const int nwg = gx * gridDim.y;
  const int flat = blockIdx.y * gx + blockIdx.x;
  const int tile = (flat & 7) * (nwg >> 3) + (flat >> 3);
  const int bm = (tile / gx) * 256, bn = (tile % gx) * BN;

  const size_t rs = (size_t)K * 2;
  const char* Ag = (const char*)A + (size_t)bm * rs;
  const char* Bg = (const char*)W + (size_t)bn * rs;

  const int stq = tid >> 2;                         // staging row in round
  const int stslot = ((tid & 3) ^ (stq & 3)) * 16;  // pre-swizzled src slot
  const int fsl = (g4 ^ (c_ & 3)) << 4;             // frag read slot
  const int dst = tid * 16;

  f32x4 acc[2][4][NTN];
#pragma unroll
  for (int mh = 0; mh < 2; ++mh)
#pragma unroll
    for (int mt = 0; mt < 4; ++mt)
#pragma unroll
      for (int nt = 0; nt < NTN; ++nt) acc[mh][mt][nt] = (f32x4){0.f, 0.f, 0.f, 0.f};

  const int NT = K / 64;

  auto stA = [&](char* buf, int slab, int half, int kbyte) {
    load_lds16(Ag + (size_t)(half * 128 + stq) * rs + kbyte + stslot,
               buf + slab * ASLAB + half * 8192 + dst);
  };
  auto stB = [&](char* buf, int slab, int half, int kbyte) {
    load_lds16(Bg + (size_t)(half * 128 + stq) * rs + kbyte + stslot,
               buf + slab * BSLAB + half * 8192 + dst);
  };

  // ---- prologue: stage tile 0 into buffer 0, klo group then khi group ----
  stA(AL, 0, 0, 0); stA(AL, 0, 1, 0); stB(BL, 0, 0, 0);
  if constexpr (BN == 256) stB(BL, 0, 1, 0);
  stA(AL, 1, 0, 64); stA(AL, 1, 1, 64); stB(BL, 1, 0, 64);
  if constexpr (BN == 256) stB(BL, 1, 1, 64);

  const int afb = (wm * 128 + c_) * 64 + fsl;
  const int bfb = (wn * RN + c_) * 64 + fsl;

#define WAIT_TOP do { if constexpr (BN == 256) asm volatile("s_waitcnt vmcnt(4)" ::: "memory"); \
                      else                     asm volatile("s_waitcnt vmcnt(3)" ::: "memory"); \
                      __builtin_amdgcn_s_barrier(); \
                      __builtin_amdgcn_sched_barrier(0); } while (0)
#define WAIT_MID do { if constexpr (BN == 256) asm volatile("s_waitcnt vmcnt(8)" ::: "memory"); \
                      else                     asm volatile("s_waitcnt vmcnt(6)" ::: "memory"); \
                      __builtin_amdgcn_s_barrier(); \
                      __builtin_amdgcn_sched_barrier(0); } while (0)

  for (int t = 0; t < NT; ++t) {
    const char* Ac = AL + (t & 1) * ABUF;
    const char* Bc = BL + (t & 1) * BBUF;
    char* An = AL + ((t + 1) & 1) * ABUF;
    char* Bn = BL + ((t + 1) & 1) * BBUF;
    const int tn = (t + 1 < NT) ? t + 1 : 0;   // wrapped dead prefetch on last
    const int kb = tn * 128;

    WAIT_TOP;   // t's klo landed (all waves)

    // ---- issue klo(t+1): awaited at top of t+1 ----
    stA(An, 0, 0, kb); stA(An, 0, 1, kb); stB(Bn, 0, 0, kb);
    if constexpr (BN == 256) stB(Bn, 0, 1, kb);

    bf16x8 af[4], bf0[NTN];

    // ---- phase 1: slab0, mh0 ----
#pragma unroll
    for (int mt = 0; mt < 4; ++mt)
      af[mt] = *(const bf16x8*)(Ac + afb + mt * 1024);
#pragma unroll
    for (int nt = 0; nt < NTN; ++nt)
      bf0[nt] = *(const bf16x8*)(Bc + bfb + nt * 1024);
    __builtin_amdgcn_s_setprio(1);
#pragma unroll
    for (int mt = 0; mt < 4; ++mt)
#pragma unroll
      for (int nt = 0; nt < NTN; ++nt)
        acc[0][mt][nt] = __builtin_amdgcn_mfma_f32_16x16x32_bf16(af[mt], bf0[nt], acc[0][mt][nt], 0, 0, 0);
    __builtin_amdgcn_s_setprio(0);

    // ---- issue khi(t+1): awaited at mid of t+1 ----
    stA(An, 1, 0, kb + 64); stA(An, 1, 1, kb + 64); stB(Bn, 1, 0, kb + 64);
    if constexpr (BN == 256) stB(Bn, 1, 1, kb + 64);

    // ---- phase 2: slab0, mh1 (reuse bf0) ----
#pragma unroll
    for (int mt = 0; mt < 4; ++mt)
      af[mt] = *(const bf16x8*)(Ac + afb + 4096 + mt * 1024);
    __builtin_amdgcn_s_setprio(1);
#pragma unroll
    for (int mt = 0; mt < 4; ++mt)
#pragma unroll
      for (int nt = 0; nt < NTN; ++nt)
        acc[1][mt][nt] = __builtin_amdgcn_mfma_f32_16x16x32_bf16(af[mt], bf0[nt], acc[1][mt][nt], 0, 0, 0);
    __builtin_amdgcn_s_setprio(0);

    WAIT_MID;   // t's khi landed (all waves)

    // ---- phase 3: slab1, mh0 ----
#pragma unroll
    for (int mt = 0; mt < 4; ++mt)
      af[mt] = *(const bf16x8*)(Ac + ASLAB + afb + mt * 1024);
#pragma unroll
    for (int nt = 0; nt < NTN; ++nt)
      bf0[nt] = *(const bf16x8*)(Bc + BSLAB + bfb + nt * 1024);
    __builtin_amdgcn_s_setprio(1);
#pragma unroll
    for (int mt = 0; mt < 4; ++mt)
#pragma unroll
      for (int nt = 0; nt < NTN; ++nt)
        acc[0][mt][nt] = __builtin_amdgcn_mfma_f32_16x16x32_bf16(af[mt], bf0[nt], acc[0][mt][nt], 0, 0, 0);
    __builtin_amdgcn_s_setprio(0);

    // ---- phase 4: slab1, mh1 ----
#pragma unroll
    for (int mt = 0; mt < 4; ++mt)
      af[mt] = *(const bf16x8*)(Ac + ASLAB + afb + 4096 + mt * 1024);
    __builtin_amdgcn_s_setprio(1);
#pragma unroll
    for (int mt = 0; mt < 4; ++mt)
#pragma unroll
      for (int nt = 0; nt < NTN; ++nt)
        acc[1][mt][nt] = __builtin_amdgcn_mfma_f32_16x16x32_bf16(af[mt], bf0[nt], acc[1][mt][nt], 0, 0, 0);
    __builtin_amdgcn_s_setprio(0);
  }
#undef WAIT_TOP
#undef WAIT_MID

  // drain wrapped dead prefetch before LDS deallocation / endpgm
  asm volatile("s_waitcnt vmcnt(0)" ::: "memory");

  // ---- epilogue: C row = g4*4 + reg, col = c_ (verified layout) ----
#pragma unroll
  for (int mh = 0; mh < 2; ++mh)
#pragma unroll
    for (int mt = 0; mt < 4; ++mt)
#pragma unroll
      for (int r = 0; r < 4; ++r) {
        size_t row = bm + wm * 128 + mh * 64 + mt * 16 + g4 * 4 + r;
#pragma unroll
        for (int nt = 0; nt < NTN; ++nt) {
          size_t col = bn + wn * RN + nt * 16 + c_;
          float v = acc[mh][mt][nt][r];
          if (WRITE_BF16)
            ((unsigned short*)Cv)[row * N + col] = f2bf(v);
          else
            ((float*)Cv)[row * N + col] = v;
        }
      }
}

// ---------------------------------------------------------------------------
// RoPE in place on bf16.
// ---------------------------------------------------------------------------
template <int NH, int LOGNH, int ROWE, int SCALE>
__global__ __launch_bounds__(256) void rope_bf16(
    unsigned short* __restrict__ p, const float* __restrict__ cosb,
    const float* __restrict__ sinb)
{
  int idx = blockIdx.x * 256 + threadIdx.x;
  int d = idx & 63;
  int h = (idx >> 6) & (NH - 1);
  int s = (idx >> (6 + LOGNH)) & (S_ - 1);
  int b = idx >> (6 + LOGNH + 11);

  size_t off = ((size_t)b * S_ + s) * ROWE + h * HD_ + d;
  float x1 = bf2f(p[off]);
  float x2 = bf2f(p[off + 64]);
  float c1 = cosb[s * HD_ + d],      s1 = sinb[s * HD_ + d];
  float c2 = cosb[s * HD_ + d + 64], s2 = sinb[s * HD_ + d + 64];
  float o1 = x1 * c1 - x2 * s1;
  float o2 = x2 * c2 + x1 * s2;
  if (SCALE) { o1 *= 0.08838834764831845f; o2 *= 0.08838834764831845f; }
  p[off]      = f2bf(o1);
  p[off + 64] = f2bf(o2);
}

// ---------------------------------------------------------------------------
// Causal flash attention, swapped-operand 32x32x16 MFMA (unchanged from R4).
// ---------------------------------------------------------------------------
__global__ __launch_bounds__(256) void attn_fwd_bf16(
    const unsigned short* __restrict__ QKV, unsigned short* __restrict__ O)
{
  __shared__ __align__(16) char lds[65536];   // K: 2x16KB @0, V^T: 2x16KB @32768

  const int tid = threadIdx.x;
  const int lane = tid & 63;
  const int wq = tid >> 6;
  const int ql = lane & 31;
  const int hi = lane >> 5;

  const int bid = blockIdx.x;
  const int halfg = bid >> 8, rem = bid & 255;
  const int bh = rem >> 3, a2 = rem & 7;
  const int qt = halfg ? (15 - 2 * a2) : (2 * a2);
  const int b = bh >> 4, h = bh & 15, kh = h >> 2;
  const int q0 = qt * 128;
  const int qglob = q0 + wq * 32 + ql;
  const int ktmax_w = (q0 + wq * 32 + 31) >> 6;
  const int ntiles = 2 * qt + 2;

  bf16x8 qf[8];
  {
    const unsigned short* qsrc =
        QKV + ((size_t)(b * S_) + qglob) * QSTRIDE + h * HD_ + hi * 8;
#pragma unroll
    for (int ds = 0; ds < 8; ++ds) qf[ds] = *(const bf16x8*)(qsrc + ds * 16);
  }

  f32x16 acc[4];
#pragma unroll
  for (int dt = 0; dt < 4; ++dt)
#pragma unroll
    for (int r = 0; r < 16; ++r) acc[dt][r] = 0.f;
  float m_ = -3.0e38f, l_ = 0.f;

  const char* Kg = (const char*)(QKV + (size_t)b * S_ * QSTRIDE + 2048 + kh * HD_);
  const unsigned short* Vg = QKV + (size_t)b * S_ * QSTRIDE + 2560 + kh * HD_;

  const int dc = tid & 15;
  const int kq4 = (tid >> 4) * 4;
  bf16x8 vr[4];

#pragma unroll
  for (int p = 0; p < 4; ++p) {
    int db = p * 4096 + tid * 16;
    int row = db >> 8;
    int cb = (db & 255) ^ ((row & 7) << 4);
    load_lds16(Kg + (size_t)row * (QSTRIDE * 2) + cb, lds + db);
  }
  {
    const unsigned short* vs = Vg + (size_t)kq4 * QSTRIDE + dc * 8;
#pragma unroll
    for (int i = 0; i < 4; ++i) vr[i] = *(const bf16x8*)(vs + i * QSTRIDE);
#pragma unroll
    for (int s = 0; s < 8; ++s) {
      int j = (dc + s) & 7;
      int d = dc * 8 + j;
      uint w0 = (uint)(unsigned short)vr[0][j] | ((uint)(unsigned short)vr[1][j] << 16);
      uint w1 = (uint)(unsigned short)vr[2][j] | ((uint)(unsigned short)vr[3][j] << 16);
      *(uint2*)(lds + 32768 + d * 128 + ((kq4 * 2) ^ (j << 4))) = make_uint2(w0, w1);
    }
  }
  __syncthreads();

  for (int kt = 0; kt < ntiles; ++kt) {
    const int cur = kt & 1;
    const bool pf = (kt + 1 < ntiles);

    if (pf) {
#pragma unroll
      for (int p = 0; p < 4; ++p) {
        int db = p * 4096 + tid * 16;
        int row = db >> 8;
        int cb = (db & 255) ^ ((row & 7) << 4);
        load_lds16(Kg + (size_t)((kt + 1) * 64 + row) * (QSTRIDE * 2) + cb,
                   lds + (cur ^ 1) * 16384 + db);
      }
      const unsigned short* vs = Vg + (size_t)((kt + 1) * 64 + kq4) * QSTRIDE + dc * 8;
#pragma unroll
      for (int i = 0; i < 4; ++i) vr[i] = *(const bf16x8*)(vs + i * QSTRIDE);
    }

    if (kt <= ktmax_w) {
      const char* ksc = lds + cur * 16384;
      const char* vtc = lds + 32768 + cur * 16384;
#pragma unroll
      for (int ks2 = 0; ks2 < 2; ++ks2) {
        f32x16 s;
#pragma unroll
        for (int r = 0; r < 16; ++r) s[r] = 0.f;
        const int kk = ks2 * 32 + ql;
        const char* krow = ksc + kk * 256;
        const int ksw = (kk & 7) << 4;
#pragma unroll
        for (int ds = 0; ds < 8; ++ds) {
          bf16x8 kf = *(const bf16x8*)(krow + ((ds * 32 + hi * 16) ^ ksw));
          s = __builtin_amdgcn_mfma_f32_32x32x16_bf16(kf, qf[ds], s, 0, 0, 0);
        }

        if (kt == ktmax_w) {
          const int kb = kt * 64 + ks2 * 32 + 4 * hi;
#pragma unroll
          for (int r = 0; r < 16; ++r) {
            int kg = kb + (r & 3) + 8 * (r >> 2);
            if (kg > qglob) s[r] = -3.0e38f;
          }
        }

        float mx = s[0];
#pragma unroll
        for (int r = 1; r < 16; ++r) mx = fmaxf(mx, s[r]);
        mx = fmaxf(mx, __shfl_xor(mx, 32));
        const bool nd = mx > m_ + 8.f;
        float fr = 1.f;
        if (__any(nd)) {
          float mn = nd ? mx : m_;
          fr = nd ? exp2f((m_ - mn) * L2E) : 1.f;
          m_ = mn;
#pragma unroll
          for (int dt = 0; dt < 4; ++dt)
#pragma unroll
            for (int r = 0; r < 16; ++r) acc[dt][r] *= fr;
        }
        float pr[16];
        float sum = 0.f;
#pragma unroll
        for (int r = 0; r < 16; ++r) {
          pr[r] = exp2f((s[r] - m_) * L2E);
          sum += pr[r];
        }
        sum += __shfl_xor(sum, 32);
        l_ = l_ * fr + sum;

        uint wA0 = cvtpk_bf16(pr[0], pr[1]);
        uint wA1 = cvtpk_bf16(pr[2], pr[3]);
        uint wB0 = cvtpk_bf16(pr[4], pr[5]);
        uint wB1 = cvtpk_bf16(pr[6], pr[7]);
        swap32(wA0, wB0);
        swap32(wA1, wB1);
        uint wC0 = cvtpk_bf16(pr[8], pr[9]);
        uint wC1 = cvtpk_bf16(pr[10], pr[11]);
        uint wD0 = cvtpk_bf16(pr[12], pr[13]);
        uint wD1 = cvtpk_bf16(pr[14], pr[15]);
        swap32(wC0, wD0);
        swap32(wC1, wD1);
        union { uint u[4]; bf16x8 v; } p0, p1;
        p0.u[0] = wA0; p0.u[1] = wA1; p0.u[2] = wB0; p0.u[3] = wB1;
        p1.u[0] = wC0; p1.u[1] = wC1; p1.u[2] = wD0; p1.u[3] = wD1;

#pragma unroll
        for (int dt = 0; dt < 4; ++dt) {
          const int dr = dt * 32 + ql;
          const char* vrow = vtc + dr * 128;
          const int vsw = (dr & 7) << 4;
          bf16x8 v0 = *(const bf16x8*)(vrow + ((ks2 * 64 + hi * 16) ^ vsw));
          acc[dt] = __builtin_amdgcn_mfma_f32_32x32x16_bf16(v0, p0.v, acc[dt], 0, 0, 0);
          bf16x8 v1 = *(const bf16x8*)(vrow + ((ks2 * 64 + 32 + hi * 16) ^ vsw));
          acc[dt] = __builtin_amdgcn_mfma_f32_32x32x16_bf16(v1, p1.v, acc[dt], 0, 0, 0);
        }
      }
    }

    if (pf) {
#pragma unroll
      for (int s = 0; s < 8; ++s) {
        int j = (dc + s) & 7;
        int d = dc * 8 + j;
        uint w0 = (uint)(unsigned short)vr[0][j] | ((uint)(unsigned short)vr[1][j] << 16);
        uint w1 = (uint)(unsigned short)vr[2][j] | ((uint)(unsigned short)vr[3][j] << 16);
        *(uint2*)(lds + 32768 + (cur ^ 1) * 16384 + d * 128 + ((kq4 * 2) ^ (j << 4))) =
            make_uint2(w0, w1);
      }
    }
    __syncthreads();
  }

  {
    const float inv = 1.f / l_;
    char* wsc = lds + wq * 8704;
#pragma unroll
    for (int dt = 0; dt < 4; ++dt) {
#pragma unroll
      for (int i = 0; i < 8; ++i) {
        uint wv = cvtpk_bf16(acc[dt][2 * i] * inv, acc[dt][2 * i + 1] * inv);
        int d = 2 * (i & 1) + 8 * (i >> 1) + 4 * hi + 32 * dt;
        *(uint*)(wsc + ql * 272 + d * 2) = wv;
      }
    }
#pragma unroll
    for (int j = 0; j < 8; ++j) {
      bf16x8 ov = *(const bf16x8*)(wsc + ql * 272 + hi * 128 + j * 16);
      unsigned short* ob = O + ((size_t)(b * S_) + q0 + wq * 32 + ql) * (H_ * HD_) +
                           h * HD_ + hi * 64 + j * 8;
      *(bf16x8*)ob = ov;
    }
  }
}

// ---------------------------------------------------------------------------
extern "C" void kernel_launch(void* const* d_in, const int* in_sizes, int n_in,
                              void* d_out, int out_size, void* d_ws, size_t ws_size,
                              hipStream_t stream) {
  const float* x    = (const float*)d_in[0];
  const float* cosb = (const float*)d_in[1];
  const float* sinb = (const float*)d_in[2];
  const float* wq   = (const float*)d_in[3];
  const float* wk   = (const float*)d_in[4];
  const float* wv   = (const float*)d_in[5];
  const float* wo   = (const float*)d_in[6];
  float* out        = (float*)d_out;

  unsigned short* xb     = (unsigned short*)d_ws;
  unsigned short* wqkvb  = xb + 8388608;         // x:    4096x2048
  unsigned short* wob    = wqkvb + 6291456;      // wqkv: 3072x2048
  unsigned short* qkv    = wob + 4194304;        // wo:   2048x2048
  unsigned short* attnb  = qkv + 12582912;       // qkv:  4096x3072

  dim3 blk(256);

  cast_f32_bf16<<<8192, blk, 0, stream>>>(x, xb, 8388608);
  cast_f32_bf16<<<4096, blk, 0, stream>>>(wq, wqkvb, 4194304);
  cast_f32_bf16<<<1024, blk, 0, stream>>>(wk, wqkvb + 4194304, 1048576);
  cast_f32_bf16<<<1024, blk, 0, stream>>>(wv, wqkvb + 5242880, 1048576);
  cast_f32_bf16<<<4096, blk, 0, stream>>>(wo, wob, 4194304);

  // fused QKV projection: 256x256 tiles, 192 blocks
  gemm_nt_dp<256, 1><<<dim3(12, 16), dim3(512), 0, stream>>>(
      xb, wqkvb, qkv, BS_, QSTRIDE, HID_);

  rope_bf16<16, 4, QSTRIDE, 1><<<16384, blk, 0, stream>>>(qkv, cosb, sinb);
  rope_bf16<4, 2, QSTRIDE, 0><<<4096, blk, 0, stream>>>(qkv + 2048, cosb, sinb);

  attn_fwd_bf16<<<512, blk, 0, stream>>>(qkv, attnb);

  // output projection: 256x128 tiles, 256 blocks (1/CU exactly)
  gemm_nt_dp<128, 0><<<dim3(16, 16), dim3(512), 0, stream>>>(
      attnb, wob, out, BS_, HID_, HID_);
}